// Round 5
// baseline (816.696 us; speedup 1.0000x reference)
//
#include <hip/hip_runtime.h>
#include <hip/hip_bf16.h>
#include <cstdint>
#include <cstddef>

using bf16 = __hip_bfloat16;

typedef short s16x8 __attribute__((ext_vector_type(8)));
typedef short s16x4 __attribute__((ext_vector_type(4)));
typedef float f32x4 __attribute__((ext_vector_type(4)));

#define TM 128
#define TN 128
#define BK 64

// ---- helpers -------------------------------------------------------------
__device__ inline short bfbits(float f) {           // RNE f32 -> bf16 bits
  unsigned x = __float_as_uint(f);
  return (short)((x + 0x7FFFu + ((x >> 16) & 1u)) >> 16);
}
__device__ inline float ext_val(const void* p, size_t i, int isf32) {
  return isf32 ? ((const float*)p)[i]
               : __bfloat162float(((const bf16*)p)[i]);
}
__device__ inline void ext_store(void* p, size_t i, float v, int isf32) {
  if (isf32) ((float*)p)[i] = v;
  else       ((bf16*)p)[i] = __float2bfloat16(v);
}
__device__ inline void store_val(float* p, float v) { *p = v; }
__device__ inline void store_val(bf16* p, float v) { *p = __float2bfloat16(v); }
__device__ inline float to_float(float v) { return v; }
__device__ inline float to_float(bf16 v) { return __bfloat162float(v); }

// Stage a 128x64 bf16 tile into LDS from external storage (f32 or bf16).
__device__ inline void stage_tile(const void* G, bf16* S, size_t row0,
                                  int K, int k0, int tid, int isf32) {
  if (isf32) {
    #pragma unroll
    for (int c = 0; c < 8; ++c) {
      const int ch = tid + c * 256;        // 0..2047
      const int row = ch >> 4;             // 0..127
      const int col = (ch & 15) * 4;       // 0..60
      f32x4 v = *(const f32x4*)((const float*)G + (row0 + row) * (size_t)K + k0 + col);
      s16x4 w;
      w[0] = bfbits(v[0]); w[1] = bfbits(v[1]);
      w[2] = bfbits(v[2]); w[3] = bfbits(v[3]);
      *(s16x4*)&S[row * BK + col] = w;
    }
  } else {
    #pragma unroll
    for (int c = 0; c < 4; ++c) {
      const int ch = tid + c * 256;        // 0..1023
      const int row = ch >> 3;             // 0..127
      const int col = (ch & 7) * 8;        // 0..56
      *(s16x8*)&S[row * BK + col] =
          *(const s16x8*)((const bf16*)G + (row0 + row) * (size_t)K + k0 + col);
    }
  }
}

// ---- dtype probe ---------------------------------------------------------
// Packed-bf16 storage: BOTH 16-bit halves of each u32 are bf16 bit patterns
// of ~N(0,1) samples -> exponent field in [110,140] almost surely.
// f32 storage: low half is random mantissa bits -> plausible only ~12%.
__global__ void detect_kernel(const unsigned* __restrict__ x, int* flag) {
  if (threadIdx.x == 0 && blockIdx.x == 0) {
    int plaus = 0;
    for (int i = 0; i < 256; ++i) {
      const unsigned w = x[i];
      const int elo = (int)((w >> 7) & 0xFFu);
      const int ehi = (int)((w >> 23) & 0xFFu);
      const int ok = (elo >= 110 && elo <= 140) && (ehi >= 110 && ehi <= 140);
      plaus += ok;
    }
    *flag = (plaus >= 192) ? 0 : 1;   // 0 => packed bf16, 1 => f32
  }
}

// C[m][n] = f( sum_k A[m][k]*Bw[n][k], bias[n], aux[m][n] )
// MODE 0: acc   MODE 1: sigmoid(acc+bias)   MODE 2: aux*sigmoid(acc+bias)
// AEXT: A is external (flag-typed); else internal bf16.
// CEXT: C is external (flag-typed); else internal OutT.
template <int MODE, int AEXT, int CEXT, typename OutT, typename AuxT>
__global__ __launch_bounds__(256) void gemm_bt(
    const void* __restrict__ A, const void* __restrict__ Bw,
    const void* __restrict__ bias, const AuxT* __restrict__ aux,
    void* __restrict__ C, int M, int N, int K, const int* __restrict__ flag)
{
  __shared__ bf16 As[TM * BK];
  __shared__ bf16 Bs[TN * BK];

  const int isf32 = *flag;
  const int tid  = threadIdx.x;
  const int wave = tid >> 6;
  const int lane = tid & 63;

  const int m0 = blockIdx.x * TM;
  const int n0 = blockIdx.y * TN;
  const int wm = (wave >> 1) * 64;
  const int wn = (wave & 1) * 64;

  f32x4 acc[4][4] = {};

  for (int k0 = 0; k0 < K; k0 += BK) {
    stage_tile(A,  As, m0, K, k0, tid, AEXT ? isf32 : 0);
    stage_tile(Bw, Bs, n0, K, k0, tid, isf32);
    __syncthreads();

    #pragma unroll
    for (int kk = 0; kk < BK; kk += 32) {
      s16x8 af[4], bfr[4];
      const int kcol = kk + (lane >> 4) * 8;
      #pragma unroll
      for (int i = 0; i < 4; ++i)
        af[i] = *(const s16x8*)&As[(wm + i * 16 + (lane & 15)) * BK + kcol];
      #pragma unroll
      for (int j = 0; j < 4; ++j)
        bfr[j] = *(const s16x8*)&Bs[(wn + j * 16 + (lane & 15)) * BK + kcol];
      #pragma unroll
      for (int i = 0; i < 4; ++i)
        #pragma unroll
        for (int j = 0; j < 4; ++j)
          acc[i][j] = __builtin_amdgcn_mfma_f32_16x16x32_bf16(
              af[i], bfr[j], acc[i][j], 0, 0, 0);
    }
    __syncthreads();
  }

  // epilogue: D mapping col = lane&15, row = (lane>>4)*4 + reg
  const int rq = (lane >> 4) * 4;
  const int cl = lane & 15;
  #pragma unroll
  for (int j = 0; j < 4; ++j) {
    const int gc = n0 + wn + j * 16 + cl;
    float bv = 0.0f;
    if constexpr (MODE >= 1) bv = ext_val(bias, gc, isf32);
    #pragma unroll
    for (int i = 0; i < 4; ++i) {
      const int gr = m0 + wm + i * 16 + rq;
      #pragma unroll
      for (int rr = 0; rr < 4; ++rr) {
        const size_t idx = (size_t)(gr + rr) * N + gc;
        float v = acc[i][j][rr];
        if constexpr (MODE >= 1) v = 1.0f / (1.0f + __expf(-(v + bv)));
        if constexpr (MODE == 2) v *= to_float(aux[idx]);
        if constexpr (CEXT) ext_store(C, idx, v, isf32);
        else                store_val((OutT*)C + idx, v);
      }
    }
  }
}

// One thread per (b,m). h_t = h*r_t + xi_t; z = softsign(h)*og written over xi.
template <typename RT>
__global__ __launch_bounds__(256) void scan_kernel(
    const RT* __restrict__ r, bf16* xi, const bf16* __restrict__ og,
    const void* __restrict__ mem, void* __restrict__ out,
    const int* __restrict__ flag)
{
  const int T_ = 2048, M_ = 1024;
  const size_t MN = (size_t)16384 * 1024;
  const int isf32 = *flag;
  const int idx = blockIdx.x * 256 + threadIdx.x;  // 0..8191
  float h = ext_val(mem, idx, isf32);
  const int b = idx >> 10;
  const int m = idx & 1023;
  const size_t base = (size_t)b * T_ * M_ + m;
  #pragma unroll 8
  for (int t = 0; t < T_; ++t) {
    const size_t o = base + (size_t)t * M_;
    const float rv = to_float(r[o]);
    const float xv = __bfloat162float(xi[o]);
    const float ov = __bfloat162float(og[o]);
    h = fmaf(h, rv, xv);
    xi[o] = __float2bfloat16(h / (1.0f + fabsf(h)) * ov);
  }
  ext_store(out, MN + idx, h, isf32);
}

extern "C" void kernel_launch(void* const* d_in, const int* in_sizes, int n_in,
                              void* d_out, int out_size, void* d_ws, size_t ws_size,
                              hipStream_t stream)
{
  const void* x     = d_in[0];
  const void* mem   = d_in[1];
  const void* wr_w  = d_in[2];
  const void* wr_b  = d_in[3];
  const void* wi_w  = d_in[4];
  const void* wig_w = d_in[5];
  const void* wig_b = d_in[6];
  const void* wog_w = d_in[7];
  const void* wog_b = d_in[8];
  const void* wo_w  = d_in[9];

  const int M = 16384, N = 1024, K = 1024;
  const size_t MN = (size_t)M * N;

  dim3 grid(M / TM, N / TN), block(256);
  dim3 sgrid(8192 / 256);

  if (ws_size >= MN * 8 + 16) {
    // Plan A: [tmp/r f32: 64MiB][xi bf16: 32MiB][og bf16: 32MiB][flag]
    float* tmp = (float*)d_ws;
    bf16* xi = (bf16*)((char*)d_ws + MN * 4);
    bf16* og = xi + MN;
    int* flag = (int*)((char*)d_ws + MN * 8);
    detect_kernel<<<1, 64, 0, stream>>>((const unsigned*)x, flag);
    gemm_bt<0,1,0,float,float><<<grid, block, 0, stream>>>(x, wi_w,  nullptr, (const float*)nullptr, tmp, M, N, K, flag);
    gemm_bt<2,1,0,bf16, float><<<grid, block, 0, stream>>>(x, wig_w, wig_b,   tmp,                    xi,  M, N, K, flag);
    gemm_bt<1,1,0,float,float><<<grid, block, 0, stream>>>(x, wr_w,  wr_b,    (const float*)nullptr, tmp, M, N, K, flag);
    gemm_bt<1,1,0,bf16, float><<<grid, block, 0, stream>>>(x, wog_w, wog_b,   (const float*)nullptr, og,  M, N, K, flag);
    scan_kernel<float><<<sgrid, block, 0, stream>>>(tmp, xi, og, mem, d_out, flag);
    gemm_bt<0,0,1,bf16, float><<<grid, block, 0, stream>>>(xi, wo_w, nullptr, (const float*)nullptr, d_out, M, N, K, flag);
  } else if (ws_size >= MN * 6 + 16) {
    // Plan B: all-bf16 internals: [tmp bf16][xi bf16][og bf16][flag]
    bf16* tmp = (bf16*)d_ws;
    bf16* xi = tmp + MN;
    bf16* og = xi + MN;
    int* flag = (int*)((char*)d_ws + MN * 6);
    detect_kernel<<<1, 64, 0, stream>>>((const unsigned*)x, flag);
    gemm_bt<0,1,0,bf16,bf16><<<grid, block, 0, stream>>>(x, wi_w,  nullptr, (const bf16*)nullptr, tmp, M, N, K, flag);
    gemm_bt<2,1,0,bf16,bf16><<<grid, block, 0, stream>>>(x, wig_w, wig_b,   tmp,                   xi,  M, N, K, flag);
    gemm_bt<1,1,0,bf16,bf16><<<grid, block, 0, stream>>>(x, wr_w,  wr_b,    (const bf16*)nullptr, tmp, M, N, K, flag);
    gemm_bt<1,1,0,bf16,bf16><<<grid, block, 0, stream>>>(x, wog_w, wog_b,   (const bf16*)nullptr, og,  M, N, K, flag);
    scan_kernel<bf16><<<sgrid, block, 0, stream>>>(tmp, xi, og, mem, d_out, flag);
    gemm_bt<0,0,1,bf16,bf16><<<grid, block, 0, stream>>>(xi, wo_w, nullptr, (const bf16*)nullptr, d_out, M, N, K, flag);
  }
}

// Round 6
// 601.606 us; speedup vs baseline: 1.3575x; 1.3575x over previous
//
#include <hip/hip_runtime.h>
#include <hip/hip_bf16.h>
#include <cstdint>
#include <cstddef>

using bf16 = __hip_bfloat16;

typedef short s16x8 __attribute__((ext_vector_type(8)));
typedef short s16x4 __attribute__((ext_vector_type(4)));
typedef float f32x4 __attribute__((ext_vector_type(4)));

#define TM 128
#define TN 128
#define BK 64
#define CH 32   // scan chunks
#define CS 64   // steps per chunk (CH*CS = 2048)

// ---- static device scratch (sidesteps unknown ws_size) -------------------
__device__ bf16  g_xb[16384 * 1024];      // 32 MiB: x in bf16
__device__ bf16  g_wb[5 * 1024 * 1024];   // 10 MiB: wr,wi,wig,wog,wo in bf16
__device__ bf16  g_og[16384 * 1024];      // 32 MiB: output gate
__device__ float g_cA[CH * 8192];         // scan carries / seeds
__device__ float g_cB[CH * 8192];

__device__ inline short bfbits(float f) {  // RNE f32 -> bf16 bits
  unsigned x = __float_as_uint(f);
  return (short)((x + 0x7FFFu + ((x >> 16) & 1u)) >> 16);
}
__device__ inline float sigmoidf_(float z) { return 1.0f / (1.0f + __expf(-z)); }

// ---- f32 -> bf16 bulk convert (vec4, grid-stride) ------------------------
__global__ void conv_kernel(const float* __restrict__ src, bf16* __restrict__ dst, int n4) {
  int i = blockIdx.x * blockDim.x + threadIdx.x;
  const int stride = gridDim.x * blockDim.x;
  for (; i < n4; i += stride) {
    f32x4 v = ((const f32x4*)src)[i];
    s16x4 w;
    w[0] = bfbits(v[0]); w[1] = bfbits(v[1]);
    w[2] = bfbits(v[2]); w[3] = bfbits(v[3]);
    ((s16x4*)dst)[i] = w;
  }
}

// ---- dual GEMM sharing A: acc1 = A@B1^T, acc2 = A@B2^T -------------------
// DM=0: C1(float) = sigmoid(acc1+b1); C2(bf16) = sigmoid(acc2+b2)   [r, og]
// DM=1: C1(bf16)  = acc1 * sigmoid(acc2+b2); C2 unused              [xi]
template <int DM>
__global__ __launch_bounds__(256) void gemm_dual(
    const bf16* __restrict__ A, const bf16* __restrict__ B1,
    const bf16* __restrict__ B2, const float* __restrict__ bias1,
    const float* __restrict__ bias2, void* __restrict__ C1,
    bf16* __restrict__ C2, int M, int N, int K)
{
  __shared__ bf16 As[TM * BK];
  __shared__ bf16 Bs1[TN * BK];
  __shared__ bf16 Bs2[TN * BK];

  const int tid  = threadIdx.x;
  const int wave = tid >> 6;
  const int lane = tid & 63;
  const int m0 = blockIdx.x * TM;
  const int n0 = blockIdx.y * TN;
  const int wm = (wave >> 1) * 64;
  const int wn = (wave & 1) * 64;

  f32x4 acc1[4][4] = {};
  f32x4 acc2[4][4] = {};

  for (int k0 = 0; k0 < K; k0 += BK) {
    #pragma unroll
    for (int c = 0; c < 4; ++c) {
      const int ch  = tid + c * 256;
      const int row = ch >> 3;
      const int col = (ch & 7) * 8;
      *(s16x8*)&As[row * BK + col]  = *(const s16x8*)&A[(size_t)(m0 + row) * K + k0 + col];
      *(s16x8*)&Bs1[row * BK + col] = *(const s16x8*)&B1[(size_t)(n0 + row) * K + k0 + col];
      *(s16x8*)&Bs2[row * BK + col] = *(const s16x8*)&B2[(size_t)(n0 + row) * K + k0 + col];
    }
    __syncthreads();

    #pragma unroll
    for (int kk = 0; kk < BK; kk += 32) {
      s16x8 af[4], b1f[4], b2f[4];
      const int kcol = kk + (lane >> 4) * 8;
      #pragma unroll
      for (int i = 0; i < 4; ++i)
        af[i] = *(const s16x8*)&As[(wm + i * 16 + (lane & 15)) * BK + kcol];
      #pragma unroll
      for (int j = 0; j < 4; ++j) {
        b1f[j] = *(const s16x8*)&Bs1[(wn + j * 16 + (lane & 15)) * BK + kcol];
        b2f[j] = *(const s16x8*)&Bs2[(wn + j * 16 + (lane & 15)) * BK + kcol];
      }
      #pragma unroll
      for (int i = 0; i < 4; ++i)
        #pragma unroll
        for (int j = 0; j < 4; ++j) {
          acc1[i][j] = __builtin_amdgcn_mfma_f32_16x16x32_bf16(af[i], b1f[j], acc1[i][j], 0, 0, 0);
          acc2[i][j] = __builtin_amdgcn_mfma_f32_16x16x32_bf16(af[i], b2f[j], acc2[i][j], 0, 0, 0);
        }
    }
    __syncthreads();
  }

  const int rq = (lane >> 4) * 4;
  const int cl = lane & 15;
  #pragma unroll
  for (int j = 0; j < 4; ++j) {
    const int gc = n0 + wn + j * 16 + cl;
    const float b2 = bias2[gc];
    float b1 = 0.0f;
    if constexpr (DM == 0) b1 = bias1[gc];
    #pragma unroll
    for (int i = 0; i < 4; ++i) {
      const int gr = m0 + wm + i * 16 + rq;
      #pragma unroll
      for (int rr = 0; rr < 4; ++rr) {
        const size_t idx = (size_t)(gr + rr) * N + gc;
        const float v1 = acc1[i][j][rr];
        const float v2 = acc2[i][j][rr];
        if constexpr (DM == 0) {
          ((float*)C1)[idx] = sigmoidf_(v1 + b1);
          C2[idx] = __float2bfloat16(sigmoidf_(v2 + b2));
        } else {
          ((bf16*)C1)[idx] = __float2bfloat16(v1 * sigmoidf_(v2 + b2));
        }
      }
    }
  }
}

// ---- single GEMM: y = z @ wo^T, bf16 in, f32 out -------------------------
__global__ __launch_bounds__(256) void gemm_single(
    const bf16* __restrict__ A, const bf16* __restrict__ Bw,
    float* __restrict__ C, int M, int N, int K)
{
  __shared__ bf16 As[TM * BK];
  __shared__ bf16 Bs[TN * BK];

  const int tid  = threadIdx.x;
  const int wave = tid >> 6;
  const int lane = tid & 63;
  const int m0 = blockIdx.x * TM;
  const int n0 = blockIdx.y * TN;
  const int wm = (wave >> 1) * 64;
  const int wn = (wave & 1) * 64;

  f32x4 acc[4][4] = {};

  for (int k0 = 0; k0 < K; k0 += BK) {
    #pragma unroll
    for (int c = 0; c < 4; ++c) {
      const int ch  = tid + c * 256;
      const int row = ch >> 3;
      const int col = (ch & 7) * 8;
      *(s16x8*)&As[row * BK + col] = *(const s16x8*)&A[(size_t)(m0 + row) * K + k0 + col];
      *(s16x8*)&Bs[row * BK + col] = *(const s16x8*)&Bw[(size_t)(n0 + row) * K + k0 + col];
    }
    __syncthreads();
    #pragma unroll
    for (int kk = 0; kk < BK; kk += 32) {
      s16x8 af[4], bfr[4];
      const int kcol = kk + (lane >> 4) * 8;
      #pragma unroll
      for (int i = 0; i < 4; ++i)
        af[i] = *(const s16x8*)&As[(wm + i * 16 + (lane & 15)) * BK + kcol];
      #pragma unroll
      for (int j = 0; j < 4; ++j)
        bfr[j] = *(const s16x8*)&Bs[(wn + j * 16 + (lane & 15)) * BK + kcol];
      #pragma unroll
      for (int i = 0; i < 4; ++i)
        #pragma unroll
        for (int j = 0; j < 4; ++j)
          acc[i][j] = __builtin_amdgcn_mfma_f32_16x16x32_bf16(af[i], bfr[j], acc[i][j], 0, 0, 0);
    }
    __syncthreads();
  }

  const int rq = (lane >> 4) * 4;
  const int cl = lane & 15;
  #pragma unroll
  for (int j = 0; j < 4; ++j) {
    const int gc = n0 + wn + j * 16 + cl;
    #pragma unroll
    for (int i = 0; i < 4; ++i) {
      const int gr = m0 + wm + i * 16 + rq;
      #pragma unroll
      for (int rr = 0; rr < 4; ++rr)
        C[(size_t)(gr + rr) * N + gc] = acc[i][j][rr];
    }
  }
}

// ---- chunked scan --------------------------------------------------------
// p1: per-chunk A_c = prod r, B_c = local scan from 0.
__global__ __launch_bounds__(256) void scan_p1(
    const float* __restrict__ r, const bf16* __restrict__ xi)
{
  const int bid = blockIdx.x;                 // 0..1023
  const int c   = bid >> 5;                   // chunk
  const int idx = (bid & 31) * 256 + threadIdx.x;  // channel 0..8191
  const int b = idx >> 10, m = idx & 1023;
  const size_t base = ((size_t)b * 2048 + c * CS) * 1024 + m;
  float a = 1.0f, s = 0.0f;
  #pragma unroll 16
  for (int t = 0; t < CS; ++t) {
    const size_t o = base + (size_t)t * 1024;
    const float rv = r[o];
    const float xv = __bfloat162float(xi[o]);
    a *= rv;
    s = fmaf(s, rv, xv);
  }
  g_cA[c * 8192 + idx] = a;
  g_cB[c * 8192 + idx] = s;
}

// p2: sequential chunk combine; writes seeds over g_cA; memout = final h.
__global__ __launch_bounds__(256) void scan_p2(
    const float* __restrict__ mem, float* __restrict__ memout)
{
  const int idx = blockIdx.x * 256 + threadIdx.x;  // 0..8191
  float H = mem[idx];
  #pragma unroll
  for (int c = 0; c < CH; ++c) {
    const float a = g_cA[c * 8192 + idx];
    const float s = g_cB[c * 8192 + idx];
    g_cA[c * 8192 + idx] = H;     // seed for chunk c
    H = fmaf(a, H, s);
  }
  memout[idx] = H;
}

// p3: re-scan seeded; z = softsign(h)*og written in-place over xi.
__global__ __launch_bounds__(256) void scan_p3(
    const float* __restrict__ r, bf16* xi, const bf16* __restrict__ og)
{
  const int bid = blockIdx.x;
  const int c   = bid >> 5;
  const int idx = (bid & 31) * 256 + threadIdx.x;
  const int b = idx >> 10, m = idx & 1023;
  const size_t base = ((size_t)b * 2048 + c * CS) * 1024 + m;
  float h = g_cA[c * 8192 + idx];
  #pragma unroll 8
  for (int t = 0; t < CS; ++t) {
    const size_t o = base + (size_t)t * 1024;
    const float rv = r[o];
    const float xv = __bfloat162float(xi[o]);
    const float ov = __bfloat162float(og[o]);
    h = fmaf(h, rv, xv);
    xi[o] = __float2bfloat16(h / (1.0f + fabsf(h)) * ov);
  }
}

extern "C" void kernel_launch(void* const* d_in, const int* in_sizes, int n_in,
                              void* d_out, int out_size, void* d_ws, size_t ws_size,
                              hipStream_t stream)
{
  const float* x     = (const float*)d_in[0];
  const float* mem   = (const float*)d_in[1];
  const float* wr_w  = (const float*)d_in[2];
  const float* wr_b  = (const float*)d_in[3];
  const float* wi_w  = (const float*)d_in[4];
  const float* wig_w = (const float*)d_in[5];
  const float* wig_b = (const float*)d_in[6];
  const float* wog_w = (const float*)d_in[7];
  const float* wog_b = (const float*)d_in[8];
  const float* wo_w  = (const float*)d_in[9];
  float* out = (float*)d_out;

  const int M = 16384, N = 1024, K = 1024;
  const size_t MN = (size_t)M * N;

  // ws: [r f32: 64 MiB][xi bf16: 32 MiB]  (96 MiB; proven available)
  float* r  = (float*)d_ws;
  bf16*  xi = (bf16*)((char*)d_ws + MN * 4);

  bf16* xb = nullptr, *wb = nullptr, *og = nullptr;
  hipGetSymbolAddress((void**)&xb, HIP_SYMBOL(g_xb));
  hipGetSymbolAddress((void**)&wb, HIP_SYMBOL(g_wb));
  hipGetSymbolAddress((void**)&og, HIP_SYMBOL(g_og));

  dim3 block(256);

  // 1) convert x and 5 weights to bf16
  conv_kernel<<<dim3(2048), block, 0, stream>>>(x, xb, (int)(MN / 4));
  const int W4 = 1024 * 1024 / 4;
  conv_kernel<<<dim3(256), block, 0, stream>>>(wr_w,  wb + 0 * 1024 * 1024, W4);
  conv_kernel<<<dim3(256), block, 0, stream>>>(wi_w,  wb + 1 * 1024 * 1024, W4);
  conv_kernel<<<dim3(256), block, 0, stream>>>(wig_w, wb + 2 * 1024 * 1024, W4);
  conv_kernel<<<dim3(256), block, 0, stream>>>(wog_w, wb + 3 * 1024 * 1024, W4);
  conv_kernel<<<dim3(256), block, 0, stream>>>(wo_w,  wb + 4 * 1024 * 1024, W4);

  dim3 grid(M / TM, N / TN);
  // 2) r = sigmoid(x@wr^T+b), og = sigmoid(x@wog^T+b)
  gemm_dual<0><<<grid, block, 0, stream>>>(xb, wb + 0 * 1024 * 1024, wb + 3 * 1024 * 1024,
                                           wr_b, wog_b, r, og, M, N, K);
  // 3) xi = (x@wi^T) * sigmoid(x@wig^T+b)
  gemm_dual<1><<<grid, block, 0, stream>>>(xb, wb + 1 * 1024 * 1024, wb + 2 * 1024 * 1024,
                                           nullptr, wig_b, xi, nullptr, M, N, K);
  // 4) chunked scan; z in-place over xi; mem_out -> out tail (f32)
  scan_p1<<<dim3(1024), block, 0, stream>>>(r, xi);
  scan_p2<<<dim3(32),   block, 0, stream>>>(mem, out + MN);
  scan_p3<<<dim3(1024), block, 0, stream>>>(r, xi, og);
  // 5) y = z @ wo^T
  gemm_single<<<grid, block, 0, stream>>>(xi, wb + 4 * 1024 * 1024, out, M, N, K);
}

// Round 7
// 600.688 us; speedup vs baseline: 1.3596x; 1.0015x over previous
//
#include <hip/hip_runtime.h>
#include <hip/hip_bf16.h>
#include <cstdint>
#include <cstddef>

using bf16 = __hip_bfloat16;

typedef short s16x8 __attribute__((ext_vector_type(8)));
typedef short s16x4 __attribute__((ext_vector_type(4)));
typedef float f32x4 __attribute__((ext_vector_type(4)));

#define TM 128
#define TN 128
#define BK 64
#define CH 32   // scan chunks
#define CS 64   // steps per chunk (CH*CS = 2048)

// ---- static device scratch (sidesteps unknown ws_size) -------------------
__device__ __align__(16) bf16  g_xb[16384 * 1024];      // 32 MiB: x in bf16
__device__ __align__(16) bf16  g_wb[5 * 1024 * 1024];   // 10 MiB: weights bf16
__device__ __align__(16) bf16  g_og[16384 * 1024];      // 32 MiB: output gate
__device__ float g_cA[CH * 8192];                       // scan carries / seeds
__device__ float g_cB[CH * 8192];

__device__ inline short bfbits(float f) {  // RNE f32 -> bf16 bits
  unsigned x = __float_as_uint(f);
  return (short)((x + 0x7FFFu + ((x >> 16) & 1u)) >> 16);
}
__device__ inline float sigmoidf_(float z) { return 1.0f / (1.0f + __expf(-z)); }

__device__ inline void gload_lds16(const void* g, void* l) {
  __builtin_amdgcn_global_load_lds(
      (const __attribute__((address_space(1))) void*)g,
      (__attribute__((address_space(3))) void*)l, 16, 0, 0);
}

// ---- f32 -> bf16 bulk convert (vec4, grid-stride) ------------------------
__global__ void conv_kernel(const float* __restrict__ src, bf16* __restrict__ dst, int n4) {
  int i = blockIdx.x * blockDim.x + threadIdx.x;
  const int stride = gridDim.x * blockDim.x;
  for (; i < n4; i += stride) {
    f32x4 v = ((const f32x4*)src)[i];
    s16x4 w;
    w[0] = bfbits(v[0]); w[1] = bfbits(v[1]);
    w[2] = bfbits(v[2]); w[3] = bfbits(v[3]);
    ((s16x4*)dst)[i] = w;
  }
}

// ---- dual GEMM sharing A: acc1 = A@B1^T, acc2 = A@B2^T -------------------
// DM=0: C1(float) = sigmoid(acc1+b1); C2(bf16) = sigmoid(acc2+b2)   [r, og]
// DM=1: C1(bf16)  = acc1 * sigmoid(acc2+b2); C2 unused              [xi]
template <int DM>
__global__ __launch_bounds__(256) void gemm_dual(
    const bf16* __restrict__ A, const bf16* __restrict__ B1,
    const bf16* __restrict__ B2, const float* __restrict__ bias1,
    const float* __restrict__ bias2, void* __restrict__ C1,
    bf16* __restrict__ C2, int M, int N, int K)
{
  __shared__ bf16 As[TM * BK];
  __shared__ bf16 Bs1[TN * BK];
  __shared__ bf16 Bs2[TN * BK];

  const int tid  = threadIdx.x;
  const int wave = tid >> 6;
  const int lane = tid & 63;
  const int m0 = blockIdx.x * TM;
  const int n0 = blockIdx.y * TN;
  const int wm = (wave >> 1) * 64;
  const int wn = (wave & 1) * 64;

  const int subrow = lane >> 3;   // 0..7
  const int chunk  = lane & 7;    // 0..7

  f32x4 acc1[4][4] = {};
  f32x4 acc2[4][4] = {};

  for (int k0 = 0; k0 < K; k0 += BK) {
    // async staging: wave-uniform LDS base + lane*16B contiguity (m97 layout)
    #pragma unroll
    for (int j = 0; j < 4; ++j) {
      const int q = wave * 4 + j;  // 0..15, each covers 8 rows
      const size_t grow = (size_t)(q * 8 + subrow);
      gload_lds16(A  + (m0 + grow) * K + k0 + chunk * 8, (void*)&As[q * 512]);
      gload_lds16(B1 + (n0 + grow) * K + k0 + chunk * 8, (void*)&Bs1[q * 512]);
      gload_lds16(B2 + (n0 + grow) * K + k0 + chunk * 8, (void*)&Bs2[q * 512]);
    }
    __syncthreads();

    #pragma unroll
    for (int kk = 0; kk < BK; kk += 32) {
      s16x8 af[4], b1f[4], b2f[4];
      const int kcol = kk + (lane >> 4) * 8;
      #pragma unroll
      for (int i = 0; i < 4; ++i)
        af[i] = *(const s16x8*)&As[(wm + i * 16 + (lane & 15)) * BK + kcol];
      #pragma unroll
      for (int j = 0; j < 4; ++j) {
        b1f[j] = *(const s16x8*)&Bs1[(wn + j * 16 + (lane & 15)) * BK + kcol];
        b2f[j] = *(const s16x8*)&Bs2[(wn + j * 16 + (lane & 15)) * BK + kcol];
      }
      #pragma unroll
      for (int i = 0; i < 4; ++i)
        #pragma unroll
        for (int j = 0; j < 4; ++j) {
          acc1[i][j] = __builtin_amdgcn_mfma_f32_16x16x32_bf16(af[i], b1f[j], acc1[i][j], 0, 0, 0);
          acc2[i][j] = __builtin_amdgcn_mfma_f32_16x16x32_bf16(af[i], b2f[j], acc2[i][j], 0, 0, 0);
        }
    }
    __syncthreads();
  }

  const int rq = (lane >> 4) * 4;
  const int cl = lane & 15;
  #pragma unroll
  for (int j = 0; j < 4; ++j) {
    const int gc = n0 + wn + j * 16 + cl;
    const float b2 = bias2[gc];
    float b1 = 0.0f;
    if constexpr (DM == 0) b1 = bias1[gc];
    #pragma unroll
    for (int i = 0; i < 4; ++i) {
      const int gr = m0 + wm + i * 16 + rq;
      #pragma unroll
      for (int rr = 0; rr < 4; ++rr) {
        const size_t idx = (size_t)(gr + rr) * N + gc;
        const float v1 = acc1[i][j][rr];
        const float v2 = acc2[i][j][rr];
        if constexpr (DM == 0) {
          ((float*)C1)[idx] = sigmoidf_(v1 + b1);
          C2[idx] = __float2bfloat16(sigmoidf_(v2 + b2));
        } else {
          ((bf16*)C1)[idx] = __float2bfloat16(v1 * sigmoidf_(v2 + b2));
        }
      }
    }
  }
}

// ---- single GEMM: y = z @ wo^T, bf16 in, f32 out -------------------------
__global__ __launch_bounds__(256) void gemm_single(
    const bf16* __restrict__ A, const bf16* __restrict__ Bw,
    float* __restrict__ C, int M, int N, int K)
{
  __shared__ bf16 As[TM * BK];
  __shared__ bf16 Bs[TN * BK];

  const int tid  = threadIdx.x;
  const int wave = tid >> 6;
  const int lane = tid & 63;
  const int m0 = blockIdx.x * TM;
  const int n0 = blockIdx.y * TN;
  const int wm = (wave >> 1) * 64;
  const int wn = (wave & 1) * 64;

  const int subrow = lane >> 3;
  const int chunk  = lane & 7;

  f32x4 acc[4][4] = {};

  for (int k0 = 0; k0 < K; k0 += BK) {
    #pragma unroll
    for (int j = 0; j < 4; ++j) {
      const int q = wave * 4 + j;
      const size_t grow = (size_t)(q * 8 + subrow);
      gload_lds16(A  + (m0 + grow) * K + k0 + chunk * 8, (void*)&As[q * 512]);
      gload_lds16(Bw + (n0 + grow) * K + k0 + chunk * 8, (void*)&Bs[q * 512]);
    }
    __syncthreads();
    #pragma unroll
    for (int kk = 0; kk < BK; kk += 32) {
      s16x8 af[4], bfr[4];
      const int kcol = kk + (lane >> 4) * 8;
      #pragma unroll
      for (int i = 0; i < 4; ++i)
        af[i] = *(const s16x8*)&As[(wm + i * 16 + (lane & 15)) * BK + kcol];
      #pragma unroll
      for (int j = 0; j < 4; ++j)
        bfr[j] = *(const s16x8*)&Bs[(wn + j * 16 + (lane & 15)) * BK + kcol];
      #pragma unroll
      for (int i = 0; i < 4; ++i)
        #pragma unroll
        for (int j = 0; j < 4; ++j)
          acc[i][j] = __builtin_amdgcn_mfma_f32_16x16x32_bf16(af[i], bfr[j], acc[i][j], 0, 0, 0);
    }
    __syncthreads();
  }

  const int rq = (lane >> 4) * 4;
  const int cl = lane & 15;
  #pragma unroll
  for (int j = 0; j < 4; ++j) {
    const int gc = n0 + wn + j * 16 + cl;
    #pragma unroll
    for (int i = 0; i < 4; ++i) {
      const int gr = m0 + wm + i * 16 + rq;
      #pragma unroll
      for (int rr = 0; rr < 4; ++rr)
        C[(size_t)(gr + rr) * N + gc] = acc[i][j][rr];
    }
  }
}

// ---- chunked scan --------------------------------------------------------
__global__ __launch_bounds__(256) void scan_p1(
    const float* __restrict__ r, const bf16* __restrict__ xi)
{
  const int bid = blockIdx.x;                 // 0..1023
  const int c   = bid >> 5;                   // chunk
  const int idx = (bid & 31) * 256 + threadIdx.x;  // channel 0..8191
  const int b = idx >> 10, m = idx & 1023;
  const size_t base = ((size_t)b * 2048 + c * CS) * 1024 + m;
  float a = 1.0f, s = 0.0f;
  #pragma unroll 16
  for (int t = 0; t < CS; ++t) {
    const size_t o = base + (size_t)t * 1024;
    const float rv = r[o];
    const float xv = __bfloat162float(xi[o]);
    a *= rv;
    s = fmaf(s, rv, xv);
  }
  g_cA[c * 8192 + idx] = a;
  g_cB[c * 8192 + idx] = s;
}

__global__ __launch_bounds__(256) void scan_p2(
    const float* __restrict__ mem, float* __restrict__ memout)
{
  const int idx = blockIdx.x * 256 + threadIdx.x;  // 0..8191
  float H = mem[idx];
  #pragma unroll
  for (int c = 0; c < CH; ++c) {
    const float a = g_cA[c * 8192 + idx];
    const float s = g_cB[c * 8192 + idx];
    g_cA[c * 8192 + idx] = H;     // seed for chunk c
    H = fmaf(a, H, s);
  }
  memout[idx] = H;
}

__global__ __launch_bounds__(256) void scan_p3(
    const float* __restrict__ r, bf16* xi, const bf16* __restrict__ og)
{
  const int bid = blockIdx.x;
  const int c   = bid >> 5;
  const int idx = (bid & 31) * 256 + threadIdx.x;
  const int b = idx >> 10, m = idx & 1023;
  const size_t base = ((size_t)b * 2048 + c * CS) * 1024 + m;
  float h = g_cA[c * 8192 + idx];
  #pragma unroll 8
  for (int t = 0; t < CS; ++t) {
    const size_t o = base + (size_t)t * 1024;
    const float rv = r[o];
    const float xv = __bfloat162float(xi[o]);
    const float ov = __bfloat162float(og[o]);
    h = fmaf(h, rv, xv);
    xi[o] = __float2bfloat16(h / (1.0f + fabsf(h)) * ov);
  }
}

extern "C" void kernel_launch(void* const* d_in, const int* in_sizes, int n_in,
                              void* d_out, int out_size, void* d_ws, size_t ws_size,
                              hipStream_t stream)
{
  const float* x     = (const float*)d_in[0];
  const float* mem   = (const float*)d_in[1];
  const float* wr_w  = (const float*)d_in[2];
  const float* wr_b  = (const float*)d_in[3];
  const float* wi_w  = (const float*)d_in[4];
  const float* wig_w = (const float*)d_in[5];
  const float* wig_b = (const float*)d_in[6];
  const float* wog_w = (const float*)d_in[7];
  const float* wog_b = (const float*)d_in[8];
  const float* wo_w  = (const float*)d_in[9];
  float* out = (float*)d_out;

  const int M = 16384, N = 1024, K = 1024;
  const size_t MN = (size_t)M * N;

  // ws: [r f32: 64 MiB][xi bf16: 32 MiB]  (96 MiB; proven available)
  float* r  = (float*)d_ws;
  bf16*  xi = (bf16*)((char*)d_ws + MN * 4);

  bf16* xb = nullptr, *wb = nullptr, *og = nullptr;
  hipGetSymbolAddress((void**)&xb, HIP_SYMBOL(g_xb));
  hipGetSymbolAddress((void**)&wb, HIP_SYMBOL(g_wb));
  hipGetSymbolAddress((void**)&og, HIP_SYMBOL(g_og));

  dim3 block(256);

  // 1) convert x and 5 weights to bf16
  conv_kernel<<<dim3(2048), block, 0, stream>>>(x, xb, (int)(MN / 4));
  const int W4 = 1024 * 1024 / 4;
  conv_kernel<<<dim3(256), block, 0, stream>>>(wr_w,  wb + 0 * 1024 * 1024, W4);
  conv_kernel<<<dim3(256), block, 0, stream>>>(wi_w,  wb + 1 * 1024 * 1024, W4);
  conv_kernel<<<dim3(256), block, 0, stream>>>(wig_w, wb + 2 * 1024 * 1024, W4);
  conv_kernel<<<dim3(256), block, 0, stream>>>(wog_w, wb + 3 * 1024 * 1024, W4);
  conv_kernel<<<dim3(256), block, 0, stream>>>(wo_w,  wb + 4 * 1024 * 1024, W4);

  dim3 grid(M / TM, N / TN);
  // 2) r = sigmoid(x@wr^T+b), og = sigmoid(x@wog^T+b)
  gemm_dual<0><<<grid, block, 0, stream>>>(xb, wb + 0 * 1024 * 1024, wb + 3 * 1024 * 1024,
                                           wr_b, wog_b, r, og, M, N, K);
  // 3) xi = (x@wi^T) * sigmoid(x@wig^T+b)
  gemm_dual<1><<<grid, block, 0, stream>>>(xb, wb + 1 * 1024 * 1024, wb + 2 * 1024 * 1024,
                                           nullptr, wig_b, xi, nullptr, M, N, K);
  // 4) chunked scan; z in-place over xi; mem_out -> out tail (f32)
  scan_p1<<<dim3(1024), block, 0, stream>>>(r, xi);
  scan_p2<<<dim3(32),   block, 0, stream>>>(mem, out + MN);
  scan_p3<<<dim3(1024), block, 0, stream>>>(r, xi, og);
  // 5) y = z @ wo^T
  gemm_single<<<grid, block, 0, stream>>>(xi, wb + 4 * 1024 * 1024, out, M, N, K);
}